// Round 2
// baseline (1675.540 us; speedup 1.0000x reference)
//
#include <hip/hip_runtime.h>
#include <hip/hip_fp16.h>

// LSTM forecast: B=256, T_past=512, HID=512, FEAT=1, future=64 -> 576 steps.
// Grid: 128 WGs x 512 threads = 16 batch-groups (bb) x 8 hidden-groups (gb).
// Each WG: 16 batch x 64 hidden. W_hh slice persistent in fp16 MFMA B-frags.
//
// Lessons:
// R1: ordered agent atomics/__threadfence -> buffer_wbl2/inv (~20us/step).
//     All cross-WG traffic RELAXED agent scope (plain ops to MALL).
// R2 (2380) / R3 (2577) / R4 (5091): 1 poller/WG good; per-step unbalanced
//     work = straggler; per-wave flags = poller contention.
// R5 (1968us): BEST structure. 8-WG groups, 1 flag store/WG, one 32B flag
//     line polled by all waves, deferred atomics, 3 barriers/step.
// R6-R8 (2684/FAIL/2013): XCD-local sc0 exchange is DEAD: gfx950 scope bits
//     are (sc0,sc1)=CU/SE/Agent/System — sc0-only is SHADER-ENGINE scope
//     (8 CUs), not XCD. R8's token test vetoed all sub-agent-scope exchange.
// R9 (1662us): clean R5 + zero-atomic out[]: after reload every WG holds full
//     h(t); out rows 2gb,2gb+1 computed post-barrier-C as plain stores.
// R10 (FAIL): incremental exchange structure was SOUND; failure was an
//     editing scar in phase 3 that applied the c1 cell update TWICE per step
//     (absmax 1.15e-2). R11 = R10 with the clean two-line c1 update.
// R11: incremental exchange, clean. (a) phase 3 writes the WG's own 64-col
//     slice of h directly into hcur (safe after barrier A; own slice never
//     round-trips the MALL); (b) wave w polls ONLY producer w's flag and
//     loads that producer's 2KB slice (16 rows x 128B) the moment it flips;
//     wave gb skips and its lane 0 does the flag store so pollers start
//     instantly. Barrier C subsumes "all slices landed". Early producers'
//     load latency hides under the straggler window; only the LAST
//     producer's 2KB is serial.

#define TPAST 512
#define TTOT  576
#define HIDN  512
#define BW    16            // batch per WG
#define HW    64            // hidden per WG
#define NGRP  8             // WGs per batch group
#define NWG   128
#define NTHR  512
#define HSTR  520           // hcur LDS row stride (fp16); *2B=1040, 16B-aligned
#define GSTR  261           // gates LDS row stride (fp32)
#define BATCHN 256

typedef _Float16 half8   __attribute__((ext_vector_type(8)));
typedef _Float16 half2v  __attribute__((ext_vector_type(2)));
typedef float    float4v __attribute__((ext_vector_type(4)));
typedef int      int4v   __attribute__((ext_vector_type(4)));

__device__ __forceinline__ float fast_exp(float x) {
    return __builtin_amdgcn_exp2f(x * 1.44269504f);
}
__device__ __forceinline__ float fast_sigmoid(float x) {
    return __builtin_amdgcn_rcpf(1.0f + fast_exp(-x));
}
__device__ __forceinline__ float fast_tanh(float x) {
    return 1.0f - 2.0f * __builtin_amdgcn_rcpf(fast_exp(2.0f * x) + 1.0f);
}

// 32B system-scope load (sc0 sc1): bypasses L1/L2, reads fresh at MALL.
__device__ __forceinline__ void ld32_sys(const void* p, int4v& a, int4v& b) {
    asm volatile("global_load_dwordx4 %0, %2, off sc0 sc1\n\t"
                 "global_load_dwordx4 %1, %2, off offset:16 sc0 sc1\n\t"
                 "s_waitcnt vmcnt(0)"
                 : "=v"(a), "=v"(b) : "v"(p) : "memory");
}
__device__ __forceinline__ void drain_vm() {
    asm volatile("s_waitcnt vmcnt(0)" ::: "memory");
}

__global__ __launch_bounds__(NTHR, 1)
void lstm_forecast_kernel(const float* __restrict__ xseq,
                          const float* __restrict__ Wih,
                          const float* __restrict__ Whh,
                          const float* __restrict__ bih,
                          const float* __restrict__ bhh,
                          const float* __restrict__ Wdec,
                          const float* __restrict__ bdec,
                          float* __restrict__ out,
                          unsigned int* __restrict__ flagbase,
                          unsigned int* __restrict__ hbuf)   // fp16 pairs, [2][256][512]
{
    __shared__ _Float16 hcur[BW * HSTR];   // current h tile, fp16, row=batch
    __shared__ float    gates[BW * GSTR];  // staged MFMA output (16 x 256)
    __shared__ float    wdecs[HIDN];       // W_dec row
    __shared__ float    xcur[BW];

    const int tid  = threadIdx.x;
    const int bb   = blockIdx.x & 15;      // batch group
    const int gb   = blockIdx.x >> 4;      // hidden group 0..7
    const int lane = tid & 63;
    const int wave = tid >> 6;             // 0..7
    const int m    = lane & 15;            // MFMA A-row / D-col
    const int q    = lane >> 4;            // MFMA quad

    // ---- persistent W_hh B-fragments: 2 col-blocks x 16 k-steps (128 VGPRs) ----
    half8 Wf[2][16];
    {
        #pragma unroll
        for (int cbi = 0; cbi < 2; ++cbi) {
            const int col = (2 * wave + cbi) * 16 + m;        // 0..255
            const int gt  = col >> 6;                          // 0=i 1=f 2=g 3=o
            const int jl  = col & 63;
            const float* wr = Whh + (size_t)(gt * HIDN + gb * HW + jl) * HIDN;
            #pragma unroll
            for (int kk = 0; kk < 16; ++kk) {
                const int k0 = kk * 32 + q * 8;
                float4v u = *(const float4v*)(wr + k0);
                float4v v = *(const float4v*)(wr + k0 + 4);
                half8 h;
                h[0] = (_Float16)u[0]; h[1] = (_Float16)u[1];
                h[2] = (_Float16)u[2]; h[3] = (_Float16)u[3];
                h[4] = (_Float16)v[0]; h[5] = (_Float16)v[1];
                h[6] = (_Float16)v[2]; h[7] = (_Float16)v[3];
                Wf[cbi][kk] = h;
            }
        }
    }

    // ---- per-thread elementwise constants: thread -> (batch eb, hidden j0,j0+1)
    const int eb = tid >> 5;               // 0..15 (wave w owns rows 2w,2w+1)
    const int jj = tid & 31;
    const int j0 = 2 * jj;                 // 0..62
    float wih_r[2][4], bsum_r[2][4];
    #pragma unroll
    for (int p = 0; p < 2; ++p) {
        const int jg = gb * HW + j0 + p;
        #pragma unroll
        for (int gt = 0; gt < 4; ++gt) {
            const int r = gt * HIDN + jg;
            wih_r[p][gt]  = Wih[r];
            bsum_r[p][gt] = bih[r] + bhh[r];
        }
    }
    const float bdecv = bdec[0];
    float c0 = 0.01f, c1 = 0.01f;

    // ---- init ----
    {
        const _Float16 hinit = (_Float16)0.01f;
        for (int i = tid; i < BW * HSTR; i += NTHR) hcur[i] = hinit;
        wdecs[tid] = Wdec[tid];            // HIDN == NTHR
        if (tid < BW) xcur[tid] = xseq[(bb * BW + tid) * TPAST + 0];
    }
    __syncthreads();

    unsigned int* gflags = flagbase + bb * 16;   // 64B flag line per group
    const int bglob_e = bb * BW + eb;

    for (int t = 0; t < TTOT; ++t) {
        // ---- phase 1: MFMA  gates_tile = h (16x512) * W^T (512x256) ----
        float4v acc0 = {0.f, 0.f, 0.f, 0.f};
        float4v acc1 = {0.f, 0.f, 0.f, 0.f};
        const _Float16* arow = hcur + m * HSTR + q * 8;
        #pragma unroll
        for (int kk = 0; kk < 16; ++kk) {
            half8 af = *(const half8*)(arow + kk * 32);
            acc0 = __builtin_amdgcn_mfma_f32_16x16x32_f16(af, Wf[0][kk], acc0, 0, 0, 0);
            acc1 = __builtin_amdgcn_mfma_f32_16x16x32_f16(af, Wf[1][kk], acc1, 0, 0, 0);
        }
        // ---- phase 2: stage gates to LDS (C layout: col=m, row=q*4+r) ----
        {
            const int colbase = wave * 32;
            #pragma unroll
            for (int r = 0; r < 4; ++r) {
                gates[(q * 4 + r) * GSTR + colbase +      m] = acc0[r];
                gates[(q * 4 + r) * GSTR + colbase + 16 + m] = acc1[r];
            }
        }
        // prefetch next past-input (latency hides under barrier A + phase 3)
        const int tn = t + 1;
        float xq = 0.f;
        if (tn < TPAST && tid < BW) xq = xseq[(bb * BW + tid) * TPAST + tn];

        __syncthreads();   // barrier A: gates ready; hcur reads complete

        // ---- phase 3: elementwise LSTM + h store (no decoder work here) ----
        {
            const float xc = xcur[eb];
            const float* grow = gates + eb * GSTR;

            float gi = grow[       j0] + xc * wih_r[0][0] + bsum_r[0][0];
            float gf = grow[ 64  + j0] + xc * wih_r[0][1] + bsum_r[0][1];
            float gg = grow[128  + j0] + xc * wih_r[0][2] + bsum_r[0][2];
            float go = grow[192  + j0] + xc * wih_r[0][3] + bsum_r[0][3];
            c0 = fast_sigmoid(gf) * c0 + fast_sigmoid(gi) * fast_tanh(gg);
            const float h0 = fast_sigmoid(go) * fast_tanh(c0);

            gi = grow[       j0 + 1] + xc * wih_r[1][0] + bsum_r[1][0];
            gf = grow[ 64  + j0 + 1] + xc * wih_r[1][1] + bsum_r[1][1];
            gg = grow[128  + j0 + 1] + xc * wih_r[1][2] + bsum_r[1][2];
            go = grow[192  + j0 + 1] + xc * wih_r[1][3] + bsum_r[1][3];
            c1 = fast_sigmoid(gf) * c1 + fast_sigmoid(gi) * fast_tanh(gg);
            const float h1 = fast_sigmoid(go) * fast_tanh(c1);

            half2v hp; hp[0] = (_Float16)h0; hp[1] = (_Float16)h1;

            // R11: own-slice direct write into hcur (safe: after barrier A)
            *(half2v*)(hcur + eb * HSTR + gb * HW + j0) = hp;

            const unsigned int bits = __builtin_bit_cast(unsigned int, hp);
            unsigned int* hdst = hbuf
                + (size_t)((tn & 1) * BATCHN + bglob_e) * (HIDN / 2)
                + gb * (HW / 2) + jj;
            __hip_atomic_store(hdst, bits, __ATOMIC_RELAXED,
                               __HIP_MEMORY_SCOPE_AGENT);
        }

        drain_vm();        // per-wave: h stores ack'd at MALL
        __syncthreads();   // barrier B: all waves drained

        // ---- phase 4+5: arrive + incremental per-producer poll/load ----
        const unsigned int target = (unsigned int)tn;
        if (wave == gb && lane == 0)
            __hip_atomic_store(gflags + gb, target, __ATOMIC_RELAXED,
                               __HIP_MEMORY_SCOPE_AGENT);
        if (wave != gb) {
            // wave w consumes producer w's 64-col slice (16 rows x 128B)
            const unsigned int* slot = gflags + wave;
            int guard = 0;
            for (;;) {
                const unsigned int v = __hip_atomic_load(
                    slot, __ATOMIC_RELAXED, __HIP_MEMORY_SCOPE_AGENT);
                if (v >= target) break;
                __builtin_amdgcn_s_sleep(1);
                if (++guard > (1 << 22)) break;   // fail loud, not hung
            }
            __builtin_amdgcn_sched_barrier(0);   // keep loads below the spin

            const int p1 = tn & 1;
            const char* src = (const char*)hbuf
                + ((size_t)(p1 * BATCHN + bb * BW)) * (HIDN * 2)  // tile base
                + (size_t)(lane >> 2) * (HIDN * 2)                // row 0..15
                + wave * (HW * 2)                                 // producer cols
                + (lane & 3) * 32;                                // 32B chunk
            int4v a, b;
            ld32_sys(src, a, b);
            _Float16* dst = hcur + (lane >> 2) * HSTR + wave * HW
                            + (lane & 3) * 16;
            *(int4v*)(dst)     = a;
            *(int4v*)(dst + 8) = b;
        }
        __syncthreads();   // barrier C: full h(t) tile in hcur

        // ---- phase 6: decoder from the full fresh tile ----
        // out rows 2gb,2gb+1 by waves 0,1 (balanced: 2 rows/WG, plain stores)
        if (wave < 2) {
            const int brow = 2 * gb + wave;              // 0..15
            const _Float16* hr = hcur + brow * HSTR + lane * 8;
            const float*    wr = wdecs + lane * 8;
            half8 hv = *(const half8*)hr;
            float dx = 0.f;
            #pragma unroll
            for (int e = 0; e < 8; ++e) dx += (float)hv[e] * wr[e];
            dx += __shfl_down(dx, 32);
            dx += __shfl_down(dx, 16);
            dx += __shfl_down(dx, 8);
            dx += __shfl_down(dx, 4);
            dx += __shfl_down(dx, 2);
            dx += __shfl_down(dx, 1);
            if (lane == 0)
                out[(bb * BW + brow) * TTOT + t] = dx + bdecv;
        }
        // future x_{t+1} for all 16 rows (wave w covers its own rows 2w,2w+1)
        if (tn >= TPAST) {
            const _Float16* hr = hcur + eb * HSTR + jj * 16;
            const float*    wr = wdecs + jj * 16;
            float dx = 0.f;
            #pragma unroll
            for (int u = 0; u < 2; ++u) {
                half8 hv = *(const half8*)(hr + u * 8);
                #pragma unroll
                for (int e = 0; e < 8; ++e)
                    dx += (float)hv[e] * wr[u * 8 + e];
            }
            dx += __shfl_down(dx, 16);
            dx += __shfl_down(dx, 8);
            dx += __shfl_down(dx, 4);
            dx += __shfl_down(dx, 2);
            dx += __shfl_down(dx, 1);
            if ((lane & 31) == 0) xcur[eb] = dx + bdecv;  // own-wave write/read
        } else {
            if (tid < BW) xcur[tid] = xq;  // cross-wave reads ordered by barrier A
        }
    }
}

extern "C" void kernel_launch(void* const* d_in, const int* in_sizes, int n_in,
                              void* d_out, int out_size, void* d_ws, size_t ws_size,
                              hipStream_t stream) {
    (void)in_sizes; (void)n_in; (void)ws_size; (void)out_size;
    const float* xseq = (const float*)d_in[0];
    // d_in[1] = future_n scalar (fixed 64, shapes hardcoded)
    const float* Wih  = (const float*)d_in[2];
    const float* Whh  = (const float*)d_in[3];
    const float* bih  = (const float*)d_in[4];
    const float* bhh  = (const float*)d_in[5];
    const float* Wdec = (const float*)d_in[6];
    const float* bdec = (const float*)d_in[7];
    float* out = (float*)d_out;

    unsigned int* flags = (unsigned int*)d_ws;                // 16 groups x 64B
    unsigned int* hbuf  = (unsigned int*)((char*)d_ws + 8192);// [2][256][512] fp16 pairs

    hipMemsetAsync(d_ws, 0, 8192, stream);
    // no d_out memset needed: every (b,t) gets exactly one plain store
    lstm_forecast_kernel<<<dim3(NWG), dim3(NTHR), 0, stream>>>(
        xseq, Wih, Whh, bih, bhh, Wdec, bdec, out, flags, hbuf);
}